// Round 11
// baseline (10480.733 us; speedup 1.0000x reference)
//
#include <hip/hip_runtime.h>

typedef unsigned short u16;
typedef unsigned int u32;
typedef unsigned long long u64;
typedef __attribute__((ext_vector_type(8))) short short8;
typedef __attribute__((ext_vector_type(4))) float f32x4;

__device__ __forceinline__ float bf2f(u16 u) {
  union { float f; unsigned int i; } x; x.i = ((unsigned int)u) << 16; return x.f;
}
__device__ __forceinline__ u16 f2bf(float f) {
  union { float f; unsigned int i; } x; x.f = f;
  unsigned int r = x.i + 0x7FFFu + ((x.i >> 16) & 1u);
  return (u16)(r >> 16);
}
__device__ __forceinline__ float sigmf(float x) { return 1.f / (1.f + __expf(-x)); }
__device__ __forceinline__ float tanhfast(float x) { return 1.f - 2.f / (__expf(2.f * x) + 1.f); }

// ---------------------------------------------------------------------------
// elementwise fp32 -> bf16 convert
__global__ __launch_bounds__(256) void f2bf_kernel(const float* __restrict__ src,
                                                   u16* __restrict__ dst, int n) {
  int i = blockIdx.x * 256 + threadIdx.x;
  if (i < n) dst[i] = f2bf(src[i]);
}

// pack Wq|Wk|Wv -> [512][192] bf16, bq|bk|bv -> [192] fp32
__global__ __launch_bounds__(256) void pack_qkv_kernel(
    const float* __restrict__ Wq, const float* __restrict__ Wk, const float* __restrict__ Wv,
    const float* __restrict__ bq, const float* __restrict__ bk, const float* __restrict__ bv,
    u16* __restrict__ Wp, float* __restrict__ bp) {
  int i = blockIdx.x * 256 + threadIdx.x;
  if (i < 512 * 192) {
    int k = i / 192, r = i % 192, s = r >> 6, c = r & 63;
    const float* W = (s == 0) ? Wq : ((s == 1) ? Wk : Wv);
    Wp[i] = f2bf(W[k * 64 + c]);
  }
  if (i < 192) {
    int s = i >> 6, c = i & 63;
    bp[i] = ((s == 0) ? bq : ((s == 1) ? bk : bv))[c];
  }
}

// ---------------------------------------------------------------------------
// generic bf16 MFMA GEMM: C[M,N] = A[M,K] @ B[K,N] + bias.
// mode 0: plain (Cf fp32 and/or Cb bf16). mode 1: sigmoid -> Cf.
// mode 2: qkvT store -> Cf[sel][b][head][d][t] float4 along t (M=b*512+t, N=192).
__global__ __launch_bounds__(256) void gemm_bf16(
    const u16* __restrict__ A, const u16* __restrict__ B, const float* __restrict__ bias,
    float* __restrict__ Cf, u16* __restrict__ Cb, int M, int N, int K, int mode) {
  __shared__ u16 As[64][72];
  __shared__ u16 Bs[64][72];  // transposed: Bs[n][k]
  int tid = threadIdx.x;
  int tm = blockIdx.x * 64, tn = blockIdx.y * 64;
  int w = tid >> 6, L = tid & 63, m15 = L & 15, q = L >> 4;
  int lr = tid >> 3, lk = (tid & 7) * 8;

  f32x4 zero = {0.f, 0.f, 0.f, 0.f};
  f32x4 acc[4];
#pragma unroll
  for (int j = 0; j < 4; ++j) acc[j] = zero;

  for (int tk = 0; tk < K; tk += 64) {
#pragma unroll
    for (int rr = lr; rr < 64; rr += 32) {
      short8 v = *(const short8*)(A + (size_t)(tm + rr) * K + tk + lk);
      *(short8*)&As[rr][lk] = v;
    }
#pragma unroll
    for (int rr = lr; rr < 64; rr += 32) {
      short8 v = *(const short8*)(B + (size_t)(tk + rr) * N + tn + lk);
      const short* pv = (const short*)&v;
#pragma unroll
      for (int j = 0; j < 8; ++j) Bs[lk + j][rr] = (u16)pv[j];
    }
    __syncthreads();
#pragma unroll
    for (int ks = 0; ks < 2; ++ks) {
      int k0 = ks * 32 + q * 8;
      short8 a = *(const short8*)&As[w * 16 + m15][k0];
#pragma unroll
      for (int j = 0; j < 4; ++j) {
        short8 b = *(const short8*)&Bs[j * 16 + m15][k0];
        acc[j] = __builtin_amdgcn_mfma_f32_16x16x32_bf16(a, b, acc[j], 0, 0, 0);
      }
    }
    __syncthreads();
  }
  if (mode == 2) {
    int row0 = tm + w * 16 + q * 4;
    int bq_ = row0 >> 9, t0 = row0 & 511;
#pragma unroll
    for (int j = 0; j < 4; ++j) {
      int col = tn + j * 16 + m15;
      int sel = col >> 6, cc = col & 63, hd = cc >> 3, d = cc & 7;
      float bia = bias ? bias[col] : 0.f;
      f32x4 vv;
#pragma unroll
      for (int r = 0; r < 4; ++r) vv[r] = acc[j][r] + bia;
      *(f32x4*)(Cf + ((((size_t)sel * 16 + bq_) * 8 + hd) * 8 + d) * 512 + t0) = vv;
    }
    return;
  }
#pragma unroll
  for (int j = 0; j < 4; ++j) {
    int col = tn + j * 16 + m15;
    float bia = bias ? bias[col] : 0.f;
#pragma unroll
    for (int r = 0; r < 4; ++r) {
      int row = tm + w * 16 + q * 4 + r;
      float v = acc[j][r] + bia;
      if (mode == 1) v = sigmf(v);
      if (Cf) Cf[(size_t)row * N + col] = v;
      if (Cb) Cb[(size_t)row * N + col] = f2bf(v);
    }
  }
}

// ---------------------------------------------------------------------------
// Persistent LSTM scan, DIRECT-GATHER edition. 8 wgs x 512 threads; wave w
// of wg g owns hidden units 64g+8w..+7 (32 Wh gate-columns in VGPRs).
// ZERO barriers / ZERO LDS in the step loop: each lane gathers its own MFMA
// A-fragments (8 contiguous bf16 of batch row m15 = 4 consecutive tagged u64
// h_buf entries) directly into registers, agent-scope, tag-validated.
// Per step: gates from held acc -> h -> tagged u64 stores -> hs stores +
// xg(t+1) prefetch -> slack -> software-pipelined chunked gather (8 chunks x
// 8 u64, lookahead 1) interleaved with MFMA -> new acc. Waves self-sync via
// tags (max skew 1 step; parity double-buffer covers it). h_{-1}=0 => initial
// acc=0, no buffer init needed (0xAA poison never matches tag t+1<=512).
__global__ __launch_bounds__(512, 2) void lstm_kernel(
    const float* __restrict__ Wh,   // [512][2048] fp32
    const u16* __restrict__ xg,     // [8192][2048] bf16 (x@Wx + b)
    float* __restrict__ hs,         // [8192][512] fp32 out
    u64* __restrict__ h_buf)        // [2][4096] {tag, 2xbf16}
{
  int tid = threadIdx.x;
  int wv = tid >> 6, L = tid & 63, m15 = L & 15, q = L >> 4;
  int u0w = blockIdx.x * 64 + wv * 8;  // first hidden unit of this wave

  // preload Wh B-fragments into registers (step-invariant).
  // bfrag[kt][tl]: B[k=kt*32+q*8+jj][n=tl*16+m15], col=(n>>3)*512+u0w+(n&7)
  short8 bfrag[16][2];
  float cst[4] = {0.f, 0.f, 0.f, 0.f};
#pragma unroll
  for (int kt = 0; kt < 16; ++kt) {
#pragma unroll
    for (int tl = 0; tl < 2; ++tl) {
      int n = tl * 16 + m15;
      int col = (n >> 3) * 512 + u0w + (n & 7);
      short8 tmp;
#pragma unroll
      for (int jj = 0; jj < 8; ++jj)
        tmp[jj] = (short)f2bf(Wh[(size_t)(kt * 32 + q * 8 + jj) * 2048 + col]);
      bfrag[kt][tl] = tmp;
    }
  }

  // xg prefetch for t=0
  float xv[4][4];
  if (m15 < 8) {
#pragma unroll
    for (int r = 0; r < 4; ++r) {
      size_t base = ((size_t)((q * 4 + r) * 512)) * 2048 + u0w + m15;
#pragma unroll
      for (int g2 = 0; g2 < 4; ++g2) xv[g2][r] = bf2f(xg[base + g2 * 512]);
    }
  }

  // Wh-product accumulators for the CURRENT step (h_{-1}=0 -> zeros)
  f32x4 z = {0.f, 0.f, 0.f, 0.f};
  f32x4 a0e = z, a0o = z, a1e = z, a1o = z;

#pragma unroll 1
  for (int t = 0; t < 512; ++t) {
    // combine chains; acc0 = i|f cols, acc1 = g|o cols
    f32x4 acc0, acc1;
#pragma unroll
    for (int r = 0; r < 4; ++r) { acc0[r] = a0e[r] + a0o[r]; acc1[r] = a1e[r] + a1o[r]; }
    f32x4 accf, acco;
#pragma unroll
    for (int r = 0; r < 4; ++r) {
      accf[r] = __shfl_xor(acc0[r], 8);
      acco[r] = __shfl_xor(acc1[r], 8);
    }
    float hv[4] = {0.f, 0.f, 0.f, 0.f};
    unsigned int mybf[4] = {0, 0, 0, 0};
    if (m15 < 8) {
#pragma unroll
      for (int r = 0; r < 4; ++r) {
        float gi = acc0[r] + xv[0][r];
        float gf = accf[r] + xv[1][r];
        float gg = acc1[r] + xv[2][r];
        float go = acco[r] + xv[3][r];
        cst[r] = sigmf(gf) * cst[r] + sigmf(gi) * tanhfast(gg);
        hv[r] = sigmf(go) * tanhfast(cst[r]);
        mybf[r] = (unsigned int)f2bf(hv[r]);
      }
    }

    u64* hb = h_buf + (size_t)(t & 1) * 4096;
    unsigned int target = (unsigned int)(t + 1);

    // tagged h stores (skip on last step)
    if (t < 511) {
#pragma unroll
      for (int r = 0; r < 4; ++r) {
        unsigned int ob = (unsigned int)__shfl_xor((int)mybf[r], 1);
        if (m15 < 8 && (m15 & 1) == 0) {
          u64 val = ((u64)target << 32) | (u64)(mybf[r] | (ob << 16));
          __hip_atomic_store(&hb[(q * 4 + r) * 256 + ((u0w + m15) >> 1)], val,
                             __ATOMIC_RELAXED, __HIP_MEMORY_SCOPE_AGENT);
        }
      }
    }

    // hs output stores (always) + xg prefetch (t+1) — retire during slack
    if (m15 < 8) {
#pragma unroll
      for (int r = 0; r < 4; ++r)
        hs[((size_t)((q * 4 + r) * 512) + t) * 512 + u0w + m15] = hv[r];
      if (t < 511) {
#pragma unroll
        for (int r = 0; r < 4; ++r) {
          size_t base = ((size_t)((q * 4 + r) * 512 + t + 1)) * 2048 + u0w + m15;
#pragma unroll
          for (int g2 = 0; g2 < 4; ++g2) xv[g2][r] = bf2f(xg[base + g2 * 512]);
        }
      }
    }
    if (t == 511) break;

    // slack: let every wave's tagged data land at the coherence point
    __builtin_amdgcn_s_sleep(12);
    __builtin_amdgcn_s_sleep(12);

    // direct per-lane fragment gather + MFMA, software-pipelined.
    // lane's A-frag for kt: h_buf entries m15*256 + kt*16 + q*4 + {0..3}.
    // chunks of 2 kt-groups (8 u64), lookahead 1 chunk.
    a0e = z; a0o = z; a1e = z; a1o = z;
    const u64* gb = hb + m15 * 256 + q * 4;
    u64 vb[2][8];
#pragma unroll
    for (int j = 0; j < 8; ++j)   // chunk 0 = kt 0,1
      vb[0][j] = __hip_atomic_load(&gb[(j >> 2) * 16 + (j & 3)],
                                   __ATOMIC_RELAXED, __HIP_MEMORY_SCOPE_AGENT);
#pragma unroll
    for (int c = 0; c < 8; ++c) {
      if (c < 7) {  // issue chunk c+1
#pragma unroll
        for (int j = 0; j < 8; ++j)
          vb[(c + 1) & 1][j] = __hip_atomic_load(
              &gb[((c + 1) * 2 + (j >> 2)) * 16 + (j & 3)],
              __ATOMIC_RELAXED, __HIP_MEMORY_SCOPE_AGENT);
      }
      // tag-check chunk c + selective retry
      for (;;) {
        unsigned int need = 0;
#pragma unroll
        for (int j = 0; j < 8; ++j)
          need |= ((unsigned int)((unsigned int)(vb[c & 1][j] >> 32) != target)) << j;
        if (need == 0) break;
        __builtin_amdgcn_s_sleep(1);
#pragma unroll
        for (int j = 0; j < 8; ++j)
          if (need & (1u << j))
            vb[c & 1][j] = __hip_atomic_load(
                &gb[(c * 2 + (j >> 2)) * 16 + (j & 3)],
                __ATOMIC_RELAXED, __HIP_MEMORY_SCOPE_AGENT);
      }
      // unpack + MFMA the 2 kt-groups of this chunk
#pragma unroll
      for (int g2 = 0; g2 < 2; ++g2) {
        int kt = c * 2 + g2;
        short8 a;
        u32* ap = (u32*)&a;
#pragma unroll
        for (int j = 0; j < 4; ++j) ap[j] = (u32)vb[c & 1][g2 * 4 + j];
        if (kt & 1) {
          a0o = __builtin_amdgcn_mfma_f32_16x16x32_bf16(a, bfrag[kt][0], a0o, 0, 0, 0);
          a1o = __builtin_amdgcn_mfma_f32_16x16x32_bf16(a, bfrag[kt][1], a1o, 0, 0, 0);
        } else {
          a0e = __builtin_amdgcn_mfma_f32_16x16x32_bf16(a, bfrag[kt][0], a0e, 0, 0, 0);
          a1e = __builtin_amdgcn_mfma_f32_16x16x32_bf16(a, bfrag[kt][1], a1e, 0, 0, 0);
        }
      }
    }
  }
}

// ---------------------------------------------------------------------------
// LN1: y = LN(hs)*scale + bias + x ; writes fp32 + bf16. One wave per row.
__global__ __launch_bounds__(256) void ln1_kernel(
    const float* __restrict__ hsin, const float* __restrict__ x,
    const float* __restrict__ sc, const float* __restrict__ bi,
    float* __restrict__ hF, u16* __restrict__ hB) {
  int wv = threadIdx.x >> 6, ln = threadIdx.x & 63;
  size_t row = (size_t)blockIdx.x * 4 + wv;
  size_t rb = row * 512;
  float v[8];
  float s = 0.f;
#pragma unroll
  for (int j = 0; j < 8; ++j) { v[j] = hsin[rb + ln + j * 64]; s += v[j]; }
#pragma unroll
  for (int off = 32; off; off >>= 1) s += __shfl_xor(s, off);
  float mu = s * (1.f / 512.f);
  float vs = 0.f;
#pragma unroll
  for (int j = 0; j < 8; ++j) { float d = v[j] - mu; vs += d * d; }
#pragma unroll
  for (int off = 32; off; off >>= 1) vs += __shfl_xor(vs, off);
  float rs = rsqrtf(vs * (1.f / 512.f) + 1e-6f);
#pragma unroll
  for (int j = 0; j < 8; ++j) {
    int cc = ln + j * 64;
    float y = (v[j] - mu) * rs * sc[cc] + bi[cc] + x[rb + cc];
    hF[rb + cc] = y;
    hB[rb + cc] = f2bf(y);
  }
}

// LN2: out = LN(ao*gate + skip)*scale + bias
__global__ __launch_bounds__(256) void ln2_kernel(
    const float* __restrict__ ao, const float* __restrict__ gate,
    const float* __restrict__ skip, const float* __restrict__ sc,
    const float* __restrict__ bi, float* __restrict__ out) {
  int wv = threadIdx.x >> 6, ln = threadIdx.x & 63;
  size_t row = (size_t)blockIdx.x * 4 + wv;
  size_t rb = row * 512;
  float v[8];
  float s = 0.f;
#pragma unroll
  for (int j = 0; j < 8; ++j) {
    size_t ix = rb + ln + j * 64;
    v[j] = ao[ix] * gate[ix] + skip[ix];
    s += v[j];
  }
#pragma unroll
  for (int off = 32; off; off >>= 1) s += __shfl_xor(s, off);
  float mu = s * (1.f / 512.f);
  float vs = 0.f;
#pragma unroll
  for (int j = 0; j < 8; ++j) { float d = v[j] - mu; vs += d * d; }
#pragma unroll
  for (int off = 32; off; off >>= 1) vs += __shfl_xor(vs, off);
  float rs = rsqrtf(vs * (1.f / 512.f) + 1e-6f);
#pragma unroll
  for (int j = 0; j < 8; ++j) {
    int cc = ln + j * 64;
    out[rb + cc] = (v[j] - mu) * rs * sc[cc] + bi[cc];
  }
}

// ---------------------------------------------------------------------------
// attention on transposed qkvT[sel][b][head][d][t]: fully coalesced staging.
// one wg per (b, head); 512 threads = 1 query each; K/V in LDS [t][d] padded.
__global__ __launch_bounds__(512) void attn_kernel(const float* __restrict__ qkvT,
                                                   u16* __restrict__ ctx) {
  __shared__ float kL[512][9];
  __shared__ float vL[512][9];
  int tid = threadIdx.x;
  int b = blockIdx.x >> 3, hd = blockIdx.x & 7;
  const float* qb = qkvT + (((size_t)0 * 16 + b) * 8 + hd) * 8 * 512;
  const float* kb = qkvT + (((size_t)1 * 16 + b) * 8 + hd) * 8 * 512;
  const float* vb = qkvT + (((size_t)2 * 16 + b) * 8 + hd) * 8 * 512;
#pragma unroll
  for (int i = tid; i < 4096; i += 512) {
    int d = i >> 9, t = i & 511;
    kL[t][d] = kb[(size_t)d * 512 + t];
    vL[t][d] = vb[(size_t)d * 512 + t];
  }
  const float scl = 0.35355339059327373f;  // 1/sqrt(8)
  float qv[8];
#pragma unroll
  for (int d = 0; d < 8; ++d) qv[d] = qb[(size_t)d * 512 + tid] * scl;
  __syncthreads();
  float m = -1e30f, l = 0.f;
  float a[8] = {0, 0, 0, 0, 0, 0, 0, 0};
  for (int t2 = 0; t2 < 512; ++t2) {
    float s = 0.f;
#pragma unroll
    for (int d = 0; d < 8; ++d) s += qv[d] * kL[t2][d];
    float nm = fmaxf(m, s);
    float cor = __expf(m - nm);
    float e = __expf(s - nm);
    l = l * cor + e;
#pragma unroll
    for (int d = 0; d < 8; ++d) a[d] = a[d] * cor + e * vL[t2][d];
    m = nm;
  }
  float inv = 1.f / l;
  short8 o;
#pragma unroll
  for (int d = 0; d < 8; ++d) o[d] = (short)f2bf(a[d] * inv);
  *(short8*)(ctx + ((size_t)b * 512 + tid) * 64 + hd * 8) = o;
}

// ---------------------------------------------------------------------------
extern "C" void kernel_launch(void* const* d_in, const int* in_sizes, int n_in,
                              void* d_out, int out_size, void* d_ws, size_t ws_size,
                              hipStream_t stream) {
  (void)in_sizes; (void)n_in; (void)out_size; (void)ws_size;
  const float* x    = (const float*)d_in[0];
  const float* Wx   = (const float*)d_in[1];
  const float* Wh   = (const float*)d_in[2];
  const float* bls  = (const float*)d_in[3];
  const float* ln1s = (const float*)d_in[4];
  const float* ln1b = (const float*)d_in[5];
  const float* Wq   = (const float*)d_in[6];
  const float* bq   = (const float*)d_in[7];
  const float* Wk   = (const float*)d_in[8];
  const float* bk   = (const float*)d_in[9];
  const float* Wv   = (const float*)d_in[10];
  const float* bv   = (const float*)d_in[11];
  const float* Wo   = (const float*)d_in[12];
  const float* bo   = (const float*)d_in[13];
  const float* Wg   = (const float*)d_in[14];
  const float* bg   = (const float*)d_in[15];
  const float* ln2s = (const float*)d_in[16];
  const float* ln2b = (const float*)d_in[17];
  float* out = (float*)d_out;

  char* p = (char*)d_ws;
  auto alloc = [&](size_t bytes) -> char* {
    char* r = p;
    p += (bytes + 255) & ~(size_t)255;
    return r;
  };
  u64* h_buf    = (u64*)alloc((size_t)2 * 4096 * 8);
  u16* x_bf     = (u16*)alloc((size_t)8192 * 512 * 2);
  u16* Wx_bf    = (u16*)alloc((size_t)512 * 2048 * 2);
  u16* Wqkv_bf  = (u16*)alloc((size_t)512 * 192 * 2);
  float* bqkv   = (float*)alloc(192 * 4);
  u16* Wg_bf    = (u16*)alloc((size_t)512 * 512 * 2);
  u16* Wo_bf    = (u16*)alloc((size_t)64 * 512 * 2);
  u16* xg_bf    = (u16*)alloc((size_t)8192 * 2048 * 2);
  float* hs     = (float*)alloc((size_t)8192 * 512 * 4);
  float* hF     = (float*)alloc((size_t)8192 * 512 * 4);
  u16* hB       = (u16*)alloc((size_t)8192 * 512 * 2);
  float* qkvT   = (float*)alloc((size_t)3 * 16 * 8 * 8 * 512 * 4);
  float* gatep  = (float*)alloc((size_t)8192 * 512 * 4);
  u16* ctx      = (u16*)alloc((size_t)8192 * 64 * 2);
  float* ao     = (float*)alloc((size_t)8192 * 512 * 4);

  f2bf_kernel<<<16384, 256, 0, stream>>>(x, x_bf, 8192 * 512);
  f2bf_kernel<<<4096, 256, 0, stream>>>(Wx, Wx_bf, 512 * 2048);
  f2bf_kernel<<<1024, 256, 0, stream>>>(Wg, Wg_bf, 512 * 512);
  f2bf_kernel<<<128, 256, 0, stream>>>(Wo, Wo_bf, 64 * 512);
  pack_qkv_kernel<<<384, 256, 0, stream>>>(Wq, Wk, Wv, bq, bk, bv, Wqkv_bf, bqkv);

  // xg = x @ Wx + b  -> bf16 [8192,2048]
  gemm_bf16<<<dim3(128, 32), 256, 0, stream>>>(x_bf, Wx_bf, bls, nullptr, xg_bf,
                                               8192, 2048, 512, 0);
  // LSTM scan (direct per-lane gather, barrier-free) -> hs fp32 [8192,512]
  lstm_kernel<<<8, 512, 0, stream>>>(Wh, xg_bf, hs, h_buf);
  // h = LN(hs)+x  -> hF fp32, hB bf16
  ln1_kernel<<<2048, 256, 0, stream>>>(hs, x, ln1s, ln1b, hF, hB);
  // qkv = h @ [Wq|Wk|Wv] + b  -> qkvT[sel][b][head][d][t] fp32
  gemm_bf16<<<dim3(128, 3), 256, 0, stream>>>(hB, Wqkv_bf, bqkv, qkvT, nullptr,
                                              8192, 192, 512, 2);
  // gate = sigmoid(h @ Wg + bg)  -> fp32 [8192,512]
  gemm_bf16<<<dim3(128, 8), 256, 0, stream>>>(hB, Wg_bf, bg, gatep, nullptr,
                                              8192, 512, 512, 1);
  // attention -> ctx bf16 [8192,64]
  attn_kernel<<<128, 512, 0, stream>>>(qkvT, ctx);
  // attn_out = ctx @ Wo + bo -> fp32 [8192,512]
  gemm_bf16<<<dim3(128, 8), 256, 0, stream>>>(ctx, Wo_bf, bo, ao, nullptr,
                                              8192, 512, 64, 0);
  // out = LN(ao*gate + h)
  ln2_kernel<<<2048, 256, 0, stream>>>(ao, gatep, hF, ln2s, ln2b, out);
}

// Round 12
// 7662.577 us; speedup vs baseline: 1.3678x; 1.3678x over previous
//
#include <hip/hip_runtime.h>

typedef unsigned short u16;
typedef unsigned int u32;
typedef unsigned long long u64;
typedef __attribute__((ext_vector_type(8))) short short8;
typedef __attribute__((ext_vector_type(4))) float f32x4;

__device__ __forceinline__ float bf2f(u16 u) {
  union { float f; unsigned int i; } x; x.i = ((unsigned int)u) << 16; return x.f;
}
__device__ __forceinline__ u16 f2bf(float f) {
  union { float f; unsigned int i; } x; x.f = f;
  unsigned int r = x.i + 0x7FFFu + ((x.i >> 16) & 1u);
  return (u16)(r >> 16);
}
__device__ __forceinline__ float sigmf(float x) { return 1.f / (1.f + __expf(-x)); }
__device__ __forceinline__ float tanhfast(float x) { return 1.f - 2.f / (__expf(2.f * x) + 1.f); }

// ---------------------------------------------------------------------------
// elementwise fp32 -> bf16 convert
__global__ __launch_bounds__(256) void f2bf_kernel(const float* __restrict__ src,
                                                   u16* __restrict__ dst, int n) {
  int i = blockIdx.x * 256 + threadIdx.x;
  if (i < n) dst[i] = f2bf(src[i]);
}

// pack Wq|Wk|Wv -> [512][192] bf16, bq|bk|bv -> [192] fp32
__global__ __launch_bounds__(256) void pack_qkv_kernel(
    const float* __restrict__ Wq, const float* __restrict__ Wk, const float* __restrict__ Wv,
    const float* __restrict__ bq, const float* __restrict__ bk, const float* __restrict__ bv,
    u16* __restrict__ Wp, float* __restrict__ bp) {
  int i = blockIdx.x * 256 + threadIdx.x;
  if (i < 512 * 192) {
    int k = i / 192, r = i % 192, s = r >> 6, c = r & 63;
    const float* W = (s == 0) ? Wq : ((s == 1) ? Wk : Wv);
    Wp[i] = f2bf(W[k * 64 + c]);
  }
  if (i < 192) {
    int s = i >> 6, c = i & 63;
    bp[i] = ((s == 0) ? bq : ((s == 1) ? bk : bv))[c];
  }
}

// ---------------------------------------------------------------------------
// generic bf16 MFMA GEMM: C[M,N] = A[M,K] @ B[K,N] + bias.
// mode 0: plain (Cf fp32 and/or Cb bf16). mode 1: sigmoid -> Cf.
// mode 2: qkvT store -> Cf[sel][b][head][d][t] float4 along t (M=b*512+t, N=192).
__global__ __launch_bounds__(256) void gemm_bf16(
    const u16* __restrict__ A, const u16* __restrict__ B, const float* __restrict__ bias,
    float* __restrict__ Cf, u16* __restrict__ Cb, int M, int N, int K, int mode) {
  __shared__ u16 As[64][72];
  __shared__ u16 Bs[64][72];  // transposed: Bs[n][k]
  int tid = threadIdx.x;
  int tm = blockIdx.x * 64, tn = blockIdx.y * 64;
  int w = tid >> 6, L = tid & 63, m15 = L & 15, q = L >> 4;
  int lr = tid >> 3, lk = (tid & 7) * 8;

  f32x4 zero = {0.f, 0.f, 0.f, 0.f};
  f32x4 acc[4];
#pragma unroll
  for (int j = 0; j < 4; ++j) acc[j] = zero;

  for (int tk = 0; tk < K; tk += 64) {
#pragma unroll
    for (int rr = lr; rr < 64; rr += 32) {
      short8 v = *(const short8*)(A + (size_t)(tm + rr) * K + tk + lk);
      *(short8*)&As[rr][lk] = v;
    }
#pragma unroll
    for (int rr = lr; rr < 64; rr += 32) {
      short8 v = *(const short8*)(B + (size_t)(tk + rr) * N + tn + lk);
      const short* pv = (const short*)&v;
#pragma unroll
      for (int j = 0; j < 8; ++j) Bs[lk + j][rr] = (u16)pv[j];
    }
    __syncthreads();
#pragma unroll
    for (int ks = 0; ks < 2; ++ks) {
      int k0 = ks * 32 + q * 8;
      short8 a = *(const short8*)&As[w * 16 + m15][k0];
#pragma unroll
      for (int j = 0; j < 4; ++j) {
        short8 b = *(const short8*)&Bs[j * 16 + m15][k0];
        acc[j] = __builtin_amdgcn_mfma_f32_16x16x32_bf16(a, b, acc[j], 0, 0, 0);
      }
    }
    __syncthreads();
  }
  if (mode == 2) {
    int row0 = tm + w * 16 + q * 4;
    int bq_ = row0 >> 9, t0 = row0 & 511;
#pragma unroll
    for (int j = 0; j < 4; ++j) {
      int col = tn + j * 16 + m15;
      int sel = col >> 6, cc = col & 63, hd = cc >> 3, d = cc & 7;
      float bia = bias ? bias[col] : 0.f;
      f32x4 vv;
#pragma unroll
      for (int r = 0; r < 4; ++r) vv[r] = acc[j][r] + bia;
      *(f32x4*)(Cf + ((((size_t)sel * 16 + bq_) * 8 + hd) * 8 + d) * 512 + t0) = vv;
    }
    return;
  }
#pragma unroll
  for (int j = 0; j < 4; ++j) {
    int col = tn + j * 16 + m15;
    float bia = bias ? bias[col] : 0.f;
#pragma unroll
    for (int r = 0; r < 4; ++r) {
      int row = tm + w * 16 + q * 4 + r;
      float v = acc[j][r] + bia;
      if (mode == 1) v = sigmf(v);
      if (Cf) Cf[(size_t)row * N + col] = v;
      if (Cb) Cb[(size_t)row * N + col] = f2bf(v);
    }
  }
}

// ---------------------------------------------------------------------------
// Persistent LSTM scan, ALTERNATING BATCH-GROUP PIPELINE. 8 wgs x 512 thr;
// wave w of wg g owns hidden units 64g+8w..+7 (32 Wh gate-cols in VGPRs).
// Batch is split: G0 = batches 0-7, G1 = 8-15 (independent recurrences).
// Tick m advances group X=m&1 by one step (s=m>>1); 1024 ticks total.
// h_X(s) is produced at tick m and consumed at tick m+2, so its gather is
// issued at tick m (right after the tagged stores) and CHECKED a full tick
// later (during the other group's tick m+1) -> store-to-check window ~2
// ticks >= tau (the measured ~1.2-1.5us agent-scope visibility latency),
// eliminating the retry RTTs that dominated round 8's 3.96us/step.
// Same tagged u64 {s+1, 2xbf16} protocol, per-group parity double-buffered;
// ONE barrier per tick; vb registers carry the in-flight gather across it.
__global__ __launch_bounds__(512, 2) void lstm_kernel(
    const float* __restrict__ Wh,   // [512][2048] fp32
    const u16* __restrict__ xg,     // [8192][2048] bf16 (x@Wx + b)
    float* __restrict__ hs,         // [8192][512] fp32 out
    u64* __restrict__ h_buf)        // [2 groups][2 parity][2048] {tag,pair}
{
  __shared__ u16 hL[2][8][520];   // ping-pong by tick parity; 8 batch rows

  int tid = threadIdx.x;
  int wv = tid >> 6, L = tid & 63, m15 = L & 15, q = L >> 4;
  int u0w = blockIdx.x * 64 + wv * 8;

  // zero both hL buffers (h_{-1} = 0 for both groups)
  for (int i = tid; i < 2 * 8 * 520 / 2; i += 512) ((u32*)hL)[i] = 0;

  // preload Wh B-fragments (step-invariant), as round 8
  short8 bfrag[16][2];
#pragma unroll
  for (int kt = 0; kt < 16; ++kt) {
#pragma unroll
    for (int tl = 0; tl < 2; ++tl) {
      int n = tl * 16 + m15;
      int col = (n >> 3) * 512 + u0w + (n & 7);
      short8 tmp;
#pragma unroll
      for (int jj = 0; jj < 8; ++jj)
        tmp[jj] = (short)f2bf(Wh[(size_t)(kt * 32 + q * 8 + jj) * 2048 + col]);
      bfrag[kt][tl] = tmp;
    }
  }

  float cst[2][4] = {{0.f, 0.f, 0.f, 0.f}, {0.f, 0.f, 0.f, 0.f}};
  float xv[2][4][4];
  // prologue xg prefetch: step 0 of both groups (lanes q<2, m15<8 compute)
  if (q < 2 && m15 < 8) {
#pragma unroll
    for (int X = 0; X < 2; ++X)
#pragma unroll
      for (int r = 0; r < 4; ++r) {
        size_t base = ((size_t)((X * 8 + q * 4 + r) * 512)) * 2048 + u0w + m15;
#pragma unroll
        for (int g2 = 0; g2 < 4; ++g2) xv[X][g2][r] = bf2f(xg[base + g2 * 512]);
      }
  }
  __syncthreads();

  u64 vb[4];
#pragma unroll 1
  for (int m = 0; m < 1024; ++m) {
    int X = m & 1, s = m >> 1;

    // (1) MFMA: A rows = active group's 8 batches (rows m15&7, broadcast)
    f32x4 z = {0.f, 0.f, 0.f, 0.f};
    f32x4 a0e = z, a0o = z, a1e = z, a1o = z;
#pragma unroll
    for (int kt = 0; kt < 8; ++kt) {
      short8 aE = *(const short8*)&hL[m & 1][m15 & 7][(2 * kt) * 32 + q * 8];
      short8 aO = *(const short8*)&hL[m & 1][m15 & 7][(2 * kt + 1) * 32 + q * 8];
      a0e = __builtin_amdgcn_mfma_f32_16x16x32_bf16(aE, bfrag[2 * kt][0], a0e, 0, 0, 0);
      a1e = __builtin_amdgcn_mfma_f32_16x16x32_bf16(aE, bfrag[2 * kt][1], a1e, 0, 0, 0);
      a0o = __builtin_amdgcn_mfma_f32_16x16x32_bf16(aO, bfrag[2 * kt + 1][0], a0o, 0, 0, 0);
      a1o = __builtin_amdgcn_mfma_f32_16x16x32_bf16(aO, bfrag[2 * kt + 1][1], a1o, 0, 0, 0);
    }

    // (2) deferred check+fill of last tick's gather (in flight one full tick;
    // its vmcnt wait only drains vmem from >= one tick ago — already retired)
    if (m >= 1) {
      int sY = (m - 1) >> 1;
      if (sY < 511) {
        int Y = (m - 1) & 1;
        u64* hbY = h_buf + ((size_t)Y * 2 + (sY & 1)) * 2048;
        unsigned int tgt = (unsigned int)(sY + 1);
        for (;;) {
          unsigned int need = 0;
#pragma unroll
          for (int j = 0; j < 4; ++j)
            need |= ((unsigned int)((unsigned int)(vb[j] >> 32) != tgt)) << j;
          if (need == 0) break;
          __builtin_amdgcn_s_sleep(1);
#pragma unroll
          for (int j = 0; j < 4; ++j)
            if (need & (1u << j))
              vb[j] = __hip_atomic_load(&hbY[j * 512 + tid],
                                        __ATOMIC_RELAXED, __HIP_MEMORY_SCOPE_AGENT);
        }
#pragma unroll
        for (int j = 0; j < 4; ++j) {
          int e = j * 512 + tid;  // batch = e>>8, pair = e&255
          *(u32*)&hL[(m + 1) & 1][e >> 8][(e & 255) * 2] = (u32)vb[j];
        }
      }
    }

    // (3) gates for active group (C rows 0-7 live in lanes q<2)
    f32x4 acc0, acc1;
#pragma unroll
    for (int r = 0; r < 4; ++r) { acc0[r] = a0e[r] + a0o[r]; acc1[r] = a1e[r] + a1o[r]; }
    f32x4 accf, acco;
#pragma unroll
    for (int r = 0; r < 4; ++r) {
      accf[r] = __shfl_xor(acc0[r], 8);
      acco[r] = __shfl_xor(acc1[r], 8);
    }
    float hv[4] = {0.f, 0.f, 0.f, 0.f};
    unsigned int mybf[4] = {0, 0, 0, 0};
    if (q < 2 && m15 < 8) {
#pragma unroll
      for (int r = 0; r < 4; ++r) {
        float gi = acc0[r] + xv[X][0][r];
        float gf = accf[r] + xv[X][1][r];
        float gg = acc1[r] + xv[X][2][r];
        float go = acco[r] + xv[X][3][r];
        cst[X][r] = sigmf(gf) * cst[X][r] + sigmf(gi) * tanhfast(gg);
        hv[r] = sigmf(go) * tanhfast(cst[X][r]);
        mybf[r] = (unsigned int)f2bf(hv[r]);
      }
    }

    // (4) tagged stores + (5) gather issue (fresh data; checked next tick)
    u64* hbX = h_buf + ((size_t)X * 2 + (s & 1)) * 2048;
    if (s < 511) {
      unsigned int target = (unsigned int)(s + 1);
#pragma unroll
      for (int r = 0; r < 4; ++r) {
        unsigned int ob = (unsigned int)__shfl_xor((int)mybf[r], 1);
        if (q < 2 && m15 < 8 && (m15 & 1) == 0) {
          u64 val = ((u64)target << 32) | (u64)(mybf[r] | (ob << 16));
          __hip_atomic_store(&hbX[(q * 4 + r) * 256 + ((u0w + m15) >> 1)], val,
                             __ATOMIC_RELAXED, __HIP_MEMORY_SCOPE_AGENT);
        }
      }
#pragma unroll
      for (int j = 0; j < 4; ++j)
        vb[j] = __hip_atomic_load(&hbX[j * 512 + tid],
                                  __ATOMIC_RELAXED, __HIP_MEMORY_SCOPE_AGENT);
    }

    // (6) hs output stores + xg prefetch for this group's next step
    if (q < 2 && m15 < 8) {
#pragma unroll
      for (int r = 0; r < 4; ++r)
        hs[((size_t)((X * 8 + q * 4 + r) * 512) + s) * 512 + u0w + m15] = hv[r];
      if (s + 1 < 512) {
#pragma unroll
        for (int r = 0; r < 4; ++r) {
          size_t base = ((size_t)((X * 8 + q * 4 + r) * 512 + s + 1)) * 2048 + u0w + m15;
#pragma unroll
          for (int g2 = 0; g2 < 4; ++g2) xv[X][g2][r] = bf2f(xg[base + g2 * 512]);
        }
      }
    }
    __syncthreads();
  }
}

// ---------------------------------------------------------------------------
// LN1: y = LN(hs)*scale + bias + x ; writes fp32 + bf16. One wave per row.
__global__ __launch_bounds__(256) void ln1_kernel(
    const float* __restrict__ hsin, const float* __restrict__ x,
    const float* __restrict__ sc, const float* __restrict__ bi,
    float* __restrict__ hF, u16* __restrict__ hB) {
  int wv = threadIdx.x >> 6, ln = threadIdx.x & 63;
  size_t row = (size_t)blockIdx.x * 4 + wv;
  size_t rb = row * 512;
  float v[8];
  float s = 0.f;
#pragma unroll
  for (int j = 0; j < 8; ++j) { v[j] = hsin[rb + ln + j * 64]; s += v[j]; }
#pragma unroll
  for (int off = 32; off; off >>= 1) s += __shfl_xor(s, off);
  float mu = s * (1.f / 512.f);
  float vs = 0.f;
#pragma unroll
  for (int j = 0; j < 8; ++j) { float d = v[j] - mu; vs += d * d; }
#pragma unroll
  for (int off = 32; off; off >>= 1) vs += __shfl_xor(vs, off);
  float rs = rsqrtf(vs * (1.f / 512.f) + 1e-6f);
#pragma unroll
  for (int j = 0; j < 8; ++j) {
    int cc = ln + j * 64;
    float y = (v[j] - mu) * rs * sc[cc] + bi[cc] + x[rb + cc];
    hF[rb + cc] = y;
    hB[rb + cc] = f2bf(y);
  }
}

// LN2: out = LN(ao*gate + skip)*scale + bias
__global__ __launch_bounds__(256) void ln2_kernel(
    const float* __restrict__ ao, const float* __restrict__ gate,
    const float* __restrict__ skip, const float* __restrict__ sc,
    const float* __restrict__ bi, float* __restrict__ out) {
  int wv = threadIdx.x >> 6, ln = threadIdx.x & 63;
  size_t row = (size_t)blockIdx.x * 4 + wv;
  size_t rb = row * 512;
  float v[8];
  float s = 0.f;
#pragma unroll
  for (int j = 0; j < 8; ++j) {
    size_t ix = rb + ln + j * 64;
    v[j] = ao[ix] * gate[ix] + skip[ix];
    s += v[j];
  }
#pragma unroll
  for (int off = 32; off; off >>= 1) s += __shfl_xor(s, off);
  float mu = s * (1.f / 512.f);
  float vs = 0.f;
#pragma unroll
  for (int j = 0; j < 8; ++j) { float d = v[j] - mu; vs += d * d; }
#pragma unroll
  for (int off = 32; off; off >>= 1) vs += __shfl_xor(vs, off);
  float rs = rsqrtf(vs * (1.f / 512.f) + 1e-6f);
#pragma unroll
  for (int j = 0; j < 8; ++j) {
    int cc = ln + j * 64;
    out[rb + cc] = (v[j] - mu) * rs * sc[cc] + bi[cc];
  }
}

// ---------------------------------------------------------------------------
// attention on transposed qkvT[sel][b][head][d][t]: fully coalesced staging.
// one wg per (b, head); 512 threads = 1 query each; K/V in LDS [t][d] padded.
__global__ __launch_bounds__(512) void attn_kernel(const float* __restrict__ qkvT,
                                                   u16* __restrict__ ctx) {
  __shared__ float kL[512][9];
  __shared__ float vL[512][9];
  int tid = threadIdx.x;
  int b = blockIdx.x >> 3, hd = blockIdx.x & 7;
  const float* qb = qkvT + (((size_t)0 * 16 + b) * 8 + hd) * 8 * 512;
  const float* kb = qkvT + (((size_t)1 * 16 + b) * 8 + hd) * 8 * 512;
  const float* vb = qkvT + (((size_t)2 * 16 + b) * 8 + hd) * 8 * 512;
#pragma unroll
  for (int i = tid; i < 4096; i += 512) {
    int d = i >> 9, t = i & 511;
    kL[t][d] = kb[(size_t)d * 512 + t];
    vL[t][d] = vb[(size_t)d * 512 + t];
  }
  const float scl = 0.35355339059327373f;  // 1/sqrt(8)
  float qv[8];
#pragma unroll
  for (int d = 0; d < 8; ++d) qv[d] = qb[(size_t)d * 512 + tid] * scl;
  __syncthreads();
  float m = -1e30f, l = 0.f;
  float a[8] = {0, 0, 0, 0, 0, 0, 0, 0};
  for (int t2 = 0; t2 < 512; ++t2) {
    float s = 0.f;
#pragma unroll
    for (int d = 0; d < 8; ++d) s += qv[d] * kL[t2][d];
    float nm = fmaxf(m, s);
    float cor = __expf(m - nm);
    float e = __expf(s - nm);
    l = l * cor + e;
#pragma unroll
    for (int d = 0; d < 8; ++d) a[d] = a[d] * cor + e * vL[t2][d];
    m = nm;
  }
  float inv = 1.f / l;
  short8 o;
#pragma unroll
  for (int d = 0; d < 8; ++d) o[d] = (short)f2bf(a[d] * inv);
  *(short8*)(ctx + ((size_t)b * 512 + tid) * 64 + hd * 8) = o;
}

// ---------------------------------------------------------------------------
extern "C" void kernel_launch(void* const* d_in, const int* in_sizes, int n_in,
                              void* d_out, int out_size, void* d_ws, size_t ws_size,
                              hipStream_t stream) {
  (void)in_sizes; (void)n_in; (void)out_size; (void)ws_size;
  const float* x    = (const float*)d_in[0];
  const float* Wx   = (const float*)d_in[1];
  const float* Wh   = (const float*)d_in[2];
  const float* bls  = (const float*)d_in[3];
  const float* ln1s = (const float*)d_in[4];
  const float* ln1b = (const float*)d_in[5];
  const float* Wq   = (const float*)d_in[6];
  const float* bq   = (const float*)d_in[7];
  const float* Wk   = (const float*)d_in[8];
  const float* bk   = (const float*)d_in[9];
  const float* Wv   = (const float*)d_in[10];
  const float* bv   = (const float*)d_in[11];
  const float* Wo   = (const float*)d_in[12];
  const float* bo   = (const float*)d_in[13];
  const float* Wg   = (const float*)d_in[14];
  const float* bg   = (const float*)d_in[15];
  const float* ln2s = (const float*)d_in[16];
  const float* ln2b = (const float*)d_in[17];
  float* out = (float*)d_out;

  char* p = (char*)d_ws;
  auto alloc = [&](size_t bytes) -> char* {
    char* r = p;
    p += (bytes + 255) & ~(size_t)255;
    return r;
  };
  u64* h_buf    = (u64*)alloc((size_t)2 * 2 * 2048 * 8);
  u16* x_bf     = (u16*)alloc((size_t)8192 * 512 * 2);
  u16* Wx_bf    = (u16*)alloc((size_t)512 * 2048 * 2);
  u16* Wqkv_bf  = (u16*)alloc((size_t)512 * 192 * 2);
  float* bqkv   = (float*)alloc(192 * 4);
  u16* Wg_bf    = (u16*)alloc((size_t)512 * 512 * 2);
  u16* Wo_bf    = (u16*)alloc((size_t)64 * 512 * 2);
  u16* xg_bf    = (u16*)alloc((size_t)8192 * 2048 * 2);
  float* hs     = (float*)alloc((size_t)8192 * 512 * 4);
  float* hF     = (float*)alloc((size_t)8192 * 512 * 4);
  u16* hB       = (u16*)alloc((size_t)8192 * 512 * 2);
  float* qkvT   = (float*)alloc((size_t)3 * 16 * 8 * 8 * 512 * 4);
  float* gatep  = (float*)alloc((size_t)8192 * 512 * 4);
  u16* ctx      = (u16*)alloc((size_t)8192 * 64 * 2);
  float* ao     = (float*)alloc((size_t)8192 * 512 * 4);

  f2bf_kernel<<<16384, 256, 0, stream>>>(x, x_bf, 8192 * 512);
  f2bf_kernel<<<4096, 256, 0, stream>>>(Wx, Wx_bf, 512 * 2048);
  f2bf_kernel<<<1024, 256, 0, stream>>>(Wg, Wg_bf, 512 * 512);
  f2bf_kernel<<<128, 256, 0, stream>>>(Wo, Wo_bf, 64 * 512);
  pack_qkv_kernel<<<384, 256, 0, stream>>>(Wq, Wk, Wv, bq, bk, bv, Wqkv_bf, bqkv);

  // xg = x @ Wx + b  -> bf16 [8192,2048]
  gemm_bf16<<<dim3(128, 32), 256, 0, stream>>>(x_bf, Wx_bf, bls, nullptr, xg_bf,
                                               8192, 2048, 512, 0);
  // LSTM scan (alternating batch-group pipeline) -> hs fp32 [8192,512]
  lstm_kernel<<<8, 512, 0, stream>>>(Wh, xg_bf, hs, h_buf);
  // h = LN(hs)+x  -> hF fp32, hB bf16
  ln1_kernel<<<2048, 256, 0, stream>>>(hs, x, ln1s, ln1b, hF, hB);
  // qkv = h @ [Wq|Wk|Wv] + b  -> qkvT[sel][b][head][d][t] fp32
  gemm_bf16<<<dim3(128, 3), 256, 0, stream>>>(hB, Wqkv_bf, bqkv, qkvT, nullptr,
                                              8192, 192, 512, 2);
  // gate = sigmoid(h @ Wg + bg)  -> fp32 [8192,512]
  gemm_bf16<<<dim3(128, 8), 256, 0, stream>>>(hB, Wg_bf, bg, gatep, nullptr,
                                              8192, 512, 512, 1);
  // attention -> ctx bf16 [8192,64]
  attn_kernel<<<128, 512, 0, stream>>>(qkvT, ctx);
  // attn_out = ctx @ Wo + bo -> fp32 [8192,512]
  gemm_bf16<<<dim3(128, 8), 256, 0, stream>>>(ctx, Wo_bf, bo, ao, nullptr,
                                              8192, 512, 64, 0);
  // out = LN(ao*gate + h)
  ln2_kernel<<<2048, 256, 0, stream>>>(ao, gatep, hF, ln2s, ln2b, out);
}

// Round 13
// 2563.120 us; speedup vs baseline: 4.0891x; 2.9896x over previous
//
#include <hip/hip_runtime.h>

typedef unsigned short u16;
typedef unsigned int u32;
typedef unsigned long long u64;
typedef __attribute__((ext_vector_type(8))) short short8;
typedef __attribute__((ext_vector_type(4))) float f32x4;

__device__ __forceinline__ float bf2f(u16 u) {
  union { float f; unsigned int i; } x; x.i = ((unsigned int)u) << 16; return x.f;
}
__device__ __forceinline__ u16 f2bf(float f) {
  union { float f; unsigned int i; } x; x.f = f;
  unsigned int r = x.i + 0x7FFFu + ((x.i >> 16) & 1u);
  return (u16)(r >> 16);
}
__device__ __forceinline__ float sigmf(float x) { return 1.f / (1.f + __expf(-x)); }
__device__ __forceinline__ float tanhfast(float x) { return 1.f - 2.f / (__expf(2.f * x) + 1.f); }

// ---------------------------------------------------------------------------
// elementwise fp32 -> bf16 convert
__global__ __launch_bounds__(256) void f2bf_kernel(const float* __restrict__ src,
                                                   u16* __restrict__ dst, int n) {
  int i = blockIdx.x * 256 + threadIdx.x;
  if (i < n) dst[i] = f2bf(src[i]);
}

// pack Wq|Wk|Wv -> [512][192] bf16, bq|bk|bv -> [192] fp32
__global__ __launch_bounds__(256) void pack_qkv_kernel(
    const float* __restrict__ Wq, const float* __restrict__ Wk, const float* __restrict__ Wv,
    const float* __restrict__ bq, const float* __restrict__ bk, const float* __restrict__ bv,
    u16* __restrict__ Wp, float* __restrict__ bp) {
  int i = blockIdx.x * 256 + threadIdx.x;
  if (i < 512 * 192) {
    int k = i / 192, r = i % 192, s = r >> 6, c = r & 63;
    const float* W = (s == 0) ? Wq : ((s == 1) ? Wk : Wv);
    Wp[i] = f2bf(W[k * 64 + c]);
  }
  if (i < 192) {
    int s = i >> 6, c = i & 63;
    bp[i] = ((s == 0) ? bq : ((s == 1) ? bk : bv))[c];
  }
}

// ---------------------------------------------------------------------------
// generic bf16 MFMA GEMM: C[M,N] = A[M,K] @ B[K,N] + bias.
// mode 0: plain (Cf fp32 and/or Cb bf16). mode 1: sigmoid -> Cf.
// mode 2: qkvT store -> Cf[sel][b][head][d][t] float4 along t (M=b*512+t, N=192).
__global__ __launch_bounds__(256) void gemm_bf16(
    const u16* __restrict__ A, const u16* __restrict__ B, const float* __restrict__ bias,
    float* __restrict__ Cf, u16* __restrict__ Cb, int M, int N, int K, int mode) {
  __shared__ u16 As[64][72];
  __shared__ u16 Bs[64][72];  // transposed: Bs[n][k]
  int tid = threadIdx.x;
  int tm = blockIdx.x * 64, tn = blockIdx.y * 64;
  int w = tid >> 6, L = tid & 63, m15 = L & 15, q = L >> 4;
  int lr = tid >> 3, lk = (tid & 7) * 8;

  f32x4 zero = {0.f, 0.f, 0.f, 0.f};
  f32x4 acc[4];
#pragma unroll
  for (int j = 0; j < 4; ++j) acc[j] = zero;

  for (int tk = 0; tk < K; tk += 64) {
#pragma unroll
    for (int rr = lr; rr < 64; rr += 32) {
      short8 v = *(const short8*)(A + (size_t)(tm + rr) * K + tk + lk);
      *(short8*)&As[rr][lk] = v;
    }
#pragma unroll
    for (int rr = lr; rr < 64; rr += 32) {
      short8 v = *(const short8*)(B + (size_t)(tk + rr) * N + tn + lk);
      const short* pv = (const short*)&v;
#pragma unroll
      for (int j = 0; j < 8; ++j) Bs[lk + j][rr] = (u16)pv[j];
    }
    __syncthreads();
#pragma unroll
    for (int ks = 0; ks < 2; ++ks) {
      int k0 = ks * 32 + q * 8;
      short8 a = *(const short8*)&As[w * 16 + m15][k0];
#pragma unroll
      for (int j = 0; j < 4; ++j) {
        short8 b = *(const short8*)&Bs[j * 16 + m15][k0];
        acc[j] = __builtin_amdgcn_mfma_f32_16x16x32_bf16(a, b, acc[j], 0, 0, 0);
      }
    }
    __syncthreads();
  }
  if (mode == 2) {
    int row0 = tm + w * 16 + q * 4;
    int bq_ = row0 >> 9, t0 = row0 & 511;
#pragma unroll
    for (int j = 0; j < 4; ++j) {
      int col = tn + j * 16 + m15;
      int sel = col >> 6, cc = col & 63, hd = cc >> 3, d = cc & 7;
      float bia = bias ? bias[col] : 0.f;
      f32x4 vv;
#pragma unroll
      for (int r = 0; r < 4; ++r) vv[r] = acc[j][r] + bia;
      *(f32x4*)(Cf + ((((size_t)sel * 16 + bq_) * 8 + hd) * 8 + d) * 512 + t0) = vv;
    }
    return;
  }
#pragma unroll
  for (int j = 0; j < 4; ++j) {
    int col = tn + j * 16 + m15;
    float bia = bias ? bias[col] : 0.f;
#pragma unroll
    for (int r = 0; r < 4; ++r) {
      int row = tm + w * 16 + q * 4 + r;
      float v = acc[j][r] + bia;
      if (mode == 1) v = sigmf(v);
      if (Cf) Cf[(size_t)row * N + col] = v;
      if (Cb) Cb[(size_t)row * N + col] = f2bf(v);
    }
  }
}

// ---------------------------------------------------------------------------
// Persistent LSTM scan: 8 wgs x 512 threads (round-8 structure, best
// measured: 3.96us/step). wave w of wg g owns hidden units 64g+8w..+7
// (32 Wh gate-columns in VGPRs). Tagged slack protocol, ~1 RTT/step:
//   1. tagged u64 {t+1, 2xbf16} h stores (relaxed agent, fire-and-forget)
//   2. hs stores + xg(t+1) prefetch (issued before gathers: FIFO-older,
//      retire during slack, never block the tag check)
//   3. slack — ROUND 13 CHANGE: 4x s_sleep(8) (~0.85us, was ~0.43us).
//      R8's FETCH showed ~1 residual retry RTT/step (84 vs 52MB ideal);
//      the retry costs ~1.2us, the extra slack 0.42us. Net -0.7us/step
//      if skew+store/load asymmetry < 0.85us.
//   4. gather issue -> tag check -> selective retry (correctness net)
//   5. LDS fill, ONE __syncthreads.
// h_buf parity-double-buffered; tag==t+1 exact (stale parity tag t-1 and
// 0xAA poison never match).
__global__ __launch_bounds__(512, 2) void lstm_kernel(
    const float* __restrict__ Wh,   // [512][2048] fp32
    const u16* __restrict__ xg,     // [8192][2048] bf16 (x@Wx + b)
    float* __restrict__ hs,         // [8192][512] fp32 out
    u64* __restrict__ h_buf)        // [2][4096] {tag, 2xbf16}
{
  __shared__ u16 hL[2][16][520];

  int tid = threadIdx.x;
  int wv = tid >> 6, L = tid & 63, m15 = L & 15, q = L >> 4;
  int u0w = blockIdx.x * 64 + wv * 8;  // first hidden unit of this wave

  // zero hL[0] (h_{-1} = 0)
  for (int i = tid; i < 16 * 520; i += 512) ((u16*)hL[0])[i] = 0;

  // preload Wh B-fragments into registers (step-invariant).
  // bfrag[kt][tl]: B[k=kt*32+q*8+jj][n=tl*16+m15], col=(n>>3)*512+u0w+(n&7)
  short8 bfrag[16][2];
  float cst[4] = {0.f, 0.f, 0.f, 0.f};
#pragma unroll
  for (int kt = 0; kt < 16; ++kt) {
#pragma unroll
    for (int tl = 0; tl < 2; ++tl) {
      int n = tl * 16 + m15;
      int col = (n >> 3) * 512 + u0w + (n & 7);
      short8 tmp;
#pragma unroll
      for (int jj = 0; jj < 8; ++jj)
        tmp[jj] = (short)f2bf(Wh[(size_t)(kt * 32 + q * 8 + jj) * 2048 + col]);
      bfrag[kt][tl] = tmp;
    }
  }

  // xg prefetch for t=0
  float xv[4][4];
  if (m15 < 8) {
#pragma unroll
    for (int r = 0; r < 4; ++r) {
      size_t base = ((size_t)((q * 4 + r) * 512)) * 2048 + u0w + m15;
#pragma unroll
      for (int g2 = 0; g2 < 4; ++g2) xv[g2][r] = bf2f(xg[base + g2 * 512]);
    }
  }
  __syncthreads();

  int p = 0;
#pragma unroll 1
  for (int t = 0; t < 512; ++t) {
    u64* hb = h_buf + (size_t)(t & 1) * 4096;

    // 4 independent MFMA chains of depth 8 (A rows = batch, from LDS)
    f32x4 z = {0.f, 0.f, 0.f, 0.f};
    f32x4 a0e = z, a0o = z, a1e = z, a1o = z;
#pragma unroll
    for (int kt = 0; kt < 8; ++kt) {
      short8 aE = *(const short8*)&hL[p][m15][(2 * kt) * 32 + q * 8];
      short8 aO = *(const short8*)&hL[p][m15][(2 * kt + 1) * 32 + q * 8];
      a0e = __builtin_amdgcn_mfma_f32_16x16x32_bf16(aE, bfrag[2 * kt][0], a0e, 0, 0, 0);
      a1e = __builtin_amdgcn_mfma_f32_16x16x32_bf16(aE, bfrag[2 * kt][1], a1e, 0, 0, 0);
      a0o = __builtin_amdgcn_mfma_f32_16x16x32_bf16(aO, bfrag[2 * kt + 1][0], a0o, 0, 0, 0);
      a1o = __builtin_amdgcn_mfma_f32_16x16x32_bf16(aO, bfrag[2 * kt + 1][1], a1o, 0, 0, 0);
    }
    f32x4 acc0, acc1;
#pragma unroll
    for (int r = 0; r < 4; ++r) { acc0[r] = a0e[r] + a0o[r]; acc1[r] = a1e[r] + a1o[r]; }
    // acc0 = i(m15<8)|f ; acc1 = g|o. Gather f,o into low lanes via lane^8.
    f32x4 accf, acco;
#pragma unroll
    for (int r = 0; r < 4; ++r) {
      accf[r] = __shfl_xor(acc0[r], 8);
      acco[r] = __shfl_xor(acc1[r], 8);
    }
    float hv[4] = {0.f, 0.f, 0.f, 0.f};
    unsigned int mybf[4] = {0, 0, 0, 0};
    if (m15 < 8) {
#pragma unroll
      for (int r = 0; r < 4; ++r) {
        float gi = acc0[r] + xv[0][r];
        float gf = accf[r] + xv[1][r];
        float gg = acc1[r] + xv[2][r];
        float go = acco[r] + xv[3][r];
        cst[r] = sigmf(gf) * cst[r] + sigmf(gi) * tanhfast(gg);
        hv[r] = sigmf(go) * tanhfast(cst[r]);
        mybf[r] = (unsigned int)f2bf(hv[r]);
      }
    }

    if (t == 511) {  // last step: no exchange needed
      if (m15 < 8) {
#pragma unroll
        for (int r = 0; r < 4; ++r)
          hs[((size_t)((q * 4 + r) * 512) + t) * 512 + u0w + m15] = hv[r];
      }
      break;
    }

    // (1) tagged h stores: ONE relaxed agent u64 per pair — fire and forget
    unsigned int target = (unsigned int)(t + 1);
#pragma unroll
    for (int r = 0; r < 4; ++r) {
      unsigned int ob = (unsigned int)__shfl_xor((int)mybf[r], 1);
      if (m15 < 8 && (m15 & 1) == 0) {
        u64 val = ((u64)target << 32) | (u64)(mybf[r] | (ob << 16));
        __hip_atomic_store(&hb[(q * 4 + r) * 256 + ((u0w + m15) >> 1)], val,
                           __ATOMIC_RELAXED, __HIP_MEMORY_SCOPE_AGENT);
      }
    }

    // (2) off-path vmem NOW: FIFO-older than the gathers; retire in slack
    if (m15 < 8) {
#pragma unroll
      for (int r = 0; r < 4; ++r)
        hs[((size_t)((q * 4 + r) * 512) + t) * 512 + u0w + m15] = hv[r];
#pragma unroll
      for (int r = 0; r < 4; ++r) {
        size_t base = ((size_t)((q * 4 + r) * 512 + t + 1)) * 2048 + u0w + m15;
#pragma unroll
        for (int g2 = 0; g2 < 4; ++g2) xv[g2][r] = bf2f(xg[base + g2 * 512]);
      }
    }

    // (3) slack (~0.85us): cover inter-wg skew + store/load path asymmetry
    __builtin_amdgcn_s_sleep(8);
    __builtin_amdgcn_s_sleep(8);
    __builtin_amdgcn_s_sleep(8);
    __builtin_amdgcn_s_sleep(8);

    // (4) gather issue: 8 u64 per thread (32KB total), coalesced
    u64 v[8];
#pragma unroll
    for (int j = 0; j < 8; ++j)
      v[j] = __hip_atomic_load(&hb[j * 512 + tid],
                               __ATOMIC_RELAXED, __HIP_MEMORY_SCOPE_AGENT);

    // tag-check + selective retry (expected: zero rounds)
    for (;;) {
      unsigned int need = 0;
#pragma unroll
      for (int j = 0; j < 8; ++j)
        need |= ((unsigned int)((unsigned int)(v[j] >> 32) != target)) << j;
      if (need == 0) break;
#pragma unroll
      for (int j = 0; j < 8; ++j)
        if (need & (1u << j))
          v[j] = __hip_atomic_load(&hb[j * 512 + tid],
                                   __ATOMIC_RELAXED, __HIP_MEMORY_SCOPE_AGENT);
    }

    // (5) LDS fill: e = j*512+tid -> row e>>8, pair e&255 (u32 = 2 bf16)
#pragma unroll
    for (int j = 0; j < 8; ++j) {
      int e = j * 512 + tid;
      *(u32*)&hL[p ^ 1][e >> 8][(e & 255) * 2] = (u32)v[j];
    }
    __syncthreads();
    p ^= 1;
  }
}

// ---------------------------------------------------------------------------
// LN1: y = LN(hs)*scale + bias + x ; writes fp32 + bf16. One wave per row.
__global__ __launch_bounds__(256) void ln1_kernel(
    const float* __restrict__ hsin, const float* __restrict__ x,
    const float* __restrict__ sc, const float* __restrict__ bi,
    float* __restrict__ hF, u16* __restrict__ hB) {
  int wv = threadIdx.x >> 6, ln = threadIdx.x & 63;
  size_t row = (size_t)blockIdx.x * 4 + wv;
  size_t rb = row * 512;
  float v[8];
  float s = 0.f;
#pragma unroll
  for (int j = 0; j < 8; ++j) { v[j] = hsin[rb + ln + j * 64]; s += v[j]; }
#pragma unroll
  for (int off = 32; off; off >>= 1) s += __shfl_xor(s, off);
  float mu = s * (1.f / 512.f);
  float vs = 0.f;
#pragma unroll
  for (int j = 0; j < 8; ++j) { float d = v[j] - mu; vs += d * d; }
#pragma unroll
  for (int off = 32; off; off >>= 1) vs += __shfl_xor(vs, off);
  float rs = rsqrtf(vs * (1.f / 512.f) + 1e-6f);
#pragma unroll
  for (int j = 0; j < 8; ++j) {
    int cc = ln + j * 64;
    float y = (v[j] - mu) * rs * sc[cc] + bi[cc] + x[rb + cc];
    hF[rb + cc] = y;
    hB[rb + cc] = f2bf(y);
  }
}

// LN2: out = LN(ao*gate + skip)*scale + bias
__global__ __launch_bounds__(256) void ln2_kernel(
    const float* __restrict__ ao, const float* __restrict__ gate,
    const float* __restrict__ skip, const float* __restrict__ sc,
    const float* __restrict__ bi, float* __restrict__ out) {
  int wv = threadIdx.x >> 6, ln = threadIdx.x & 63;
  size_t row = (size_t)blockIdx.x * 4 + wv;
  size_t rb = row * 512;
  float v[8];
  float s = 0.f;
#pragma unroll
  for (int j = 0; j < 8; ++j) {
    size_t ix = rb + ln + j * 64;
    v[j] = ao[ix] * gate[ix] + skip[ix];
    s += v[j];
  }
#pragma unroll
  for (int off = 32; off; off >>= 1) s += __shfl_xor(s, off);
  float mu = s * (1.f / 512.f);
  float vs = 0.f;
#pragma unroll
  for (int j = 0; j < 8; ++j) { float d = v[j] - mu; vs += d * d; }
#pragma unroll
  for (int off = 32; off; off >>= 1) vs += __shfl_xor(vs, off);
  float rs = rsqrtf(vs * (1.f / 512.f) + 1e-6f);
#pragma unroll
  for (int j = 0; j < 8; ++j) {
    int cc = ln + j * 64;
    out[rb + cc] = (v[j] - mu) * rs * sc[cc] + bi[cc];
  }
}

// ---------------------------------------------------------------------------
// attention on transposed qkvT[sel][b][head][d][t]: fully coalesced staging.
// one wg per (b, head); 512 threads = 1 query each; K/V in LDS [t][d] padded.
__global__ __launch_bounds__(512) void attn_kernel(const float* __restrict__ qkvT,
                                                   u16* __restrict__ ctx) {
  __shared__ float kL[512][9];
  __shared__ float vL[512][9];
  int tid = threadIdx.x;
  int b = blockIdx.x >> 3, hd = blockIdx.x & 7;
  const float* qb = qkvT + (((size_t)0 * 16 + b) * 8 + hd) * 8 * 512;
  const float* kb = qkvT + (((size_t)1 * 16 + b) * 8 + hd) * 8 * 512;
  const float* vb = qkvT + (((size_t)2 * 16 + b) * 8 + hd) * 8 * 512;
#pragma unroll
  for (int i = tid; i < 4096; i += 512) {
    int d = i >> 9, t = i & 511;
    kL[t][d] = kb[(size_t)d * 512 + t];
    vL[t][d] = vb[(size_t)d * 512 + t];
  }
  const float scl = 0.35355339059327373f;  // 1/sqrt(8)
  float qv[8];
#pragma unroll
  for (int d = 0; d < 8; ++d) qv[d] = qb[(size_t)d * 512 + tid] * scl;
  __syncthreads();
  float m = -1e30f, l = 0.f;
  float a[8] = {0, 0, 0, 0, 0, 0, 0, 0};
  for (int t2 = 0; t2 < 512; ++t2) {
    float s = 0.f;
#pragma unroll
    for (int d = 0; d < 8; ++d) s += qv[d] * kL[t2][d];
    float nm = fmaxf(m, s);
    float cor = __expf(m - nm);
    float e = __expf(s - nm);
    l = l * cor + e;
#pragma unroll
    for (int d = 0; d < 8; ++d) a[d] = a[d] * cor + e * vL[t2][d];
    m = nm;
  }
  float inv = 1.f / l;
  short8 o;
#pragma unroll
  for (int d = 0; d < 8; ++d) o[d] = (short)f2bf(a[d] * inv);
  *(short8*)(ctx + ((size_t)b * 512 + tid) * 64 + hd * 8) = o;
}

// ---------------------------------------------------------------------------
extern "C" void kernel_launch(void* const* d_in, const int* in_sizes, int n_in,
                              void* d_out, int out_size, void* d_ws, size_t ws_size,
                              hipStream_t stream) {
  (void)in_sizes; (void)n_in; (void)out_size; (void)ws_size;
  const float* x    = (const float*)d_in[0];
  const float* Wx   = (const float*)d_in[1];
  const float* Wh   = (const float*)d_in[2];
  const float* bls  = (const float*)d_in[3];
  const float* ln1s = (const float*)d_in[4];
  const float* ln1b = (const float*)d_in[5];
  const float* Wq   = (const float*)d_in[6];
  const float* bq   = (const float*)d_in[7];
  const float* Wk   = (const float*)d_in[8];
  const float* bk   = (const float*)d_in[9];
  const float* Wv   = (const float*)d_in[10];
  const float* bv   = (const float*)d_in[11];
  const float* Wo   = (const float*)d_in[12];
  const float* bo   = (const float*)d_in[13];
  const float* Wg   = (const float*)d_in[14];
  const float* bg   = (const float*)d_in[15];
  const float* ln2s = (const float*)d_in[16];
  const float* ln2b = (const float*)d_in[17];
  float* out = (float*)d_out;

  char* p = (char*)d_ws;
  auto alloc = [&](size_t bytes) -> char* {
    char* r = p;
    p += (bytes + 255) & ~(size_t)255;
    return r;
  };
  u64* h_buf    = (u64*)alloc((size_t)2 * 4096 * 8);
  u16* x_bf     = (u16*)alloc((size_t)8192 * 512 * 2);
  u16* Wx_bf    = (u16*)alloc((size_t)512 * 2048 * 2);
  u16* Wqkv_bf  = (u16*)alloc((size_t)512 * 192 * 2);
  float* bqkv   = (float*)alloc(192 * 4);
  u16* Wg_bf    = (u16*)alloc((size_t)512 * 512 * 2);
  u16* Wo_bf    = (u16*)alloc((size_t)64 * 512 * 2);
  u16* xg_bf    = (u16*)alloc((size_t)8192 * 2048 * 2);
  float* hs     = (float*)alloc((size_t)8192 * 512 * 4);
  float* hF     = (float*)alloc((size_t)8192 * 512 * 4);
  u16* hB       = (u16*)alloc((size_t)8192 * 512 * 2);
  float* qkvT   = (float*)alloc((size_t)3 * 16 * 8 * 8 * 512 * 4);
  float* gatep  = (float*)alloc((size_t)8192 * 512 * 4);
  u16* ctx      = (u16*)alloc((size_t)8192 * 64 * 2);
  float* ao     = (float*)alloc((size_t)8192 * 512 * 4);

  f2bf_kernel<<<16384, 256, 0, stream>>>(x, x_bf, 8192 * 512);
  f2bf_kernel<<<4096, 256, 0, stream>>>(Wx, Wx_bf, 512 * 2048);
  f2bf_kernel<<<1024, 256, 0, stream>>>(Wg, Wg_bf, 512 * 512);
  f2bf_kernel<<<128, 256, 0, stream>>>(Wo, Wo_bf, 64 * 512);
  pack_qkv_kernel<<<384, 256, 0, stream>>>(Wq, Wk, Wv, bq, bk, bv, Wqkv_bf, bqkv);

  // xg = x @ Wx + b  -> bf16 [8192,2048]
  gemm_bf16<<<dim3(128, 32), 256, 0, stream>>>(x_bf, Wx_bf, bls, nullptr, xg_bf,
                                               8192, 2048, 512, 0);
  // LSTM scan -> hs fp32 [8192,512]
  lstm_kernel<<<8, 512, 0, stream>>>(Wh, xg_bf, hs, h_buf);
  // h = LN(hs)+x  -> hF fp32, hB bf16
  ln1_kernel<<<2048, 256, 0, stream>>>(hs, x, ln1s, ln1b, hF, hB);
  // qkv = h @ [Wq|Wk|Wv] + b  -> qkvT[sel][b][head][d][t] fp32
  gemm_bf16<<<dim3(128, 3), 256, 0, stream>>>(hB, Wqkv_bf, bqkv, qkvT, nullptr,
                                              8192, 192, 512, 2);
  // gate = sigmoid(h @ Wg + bg)  -> fp32 [8192,512]
  gemm_bf16<<<dim3(128, 8), 256, 0, stream>>>(hB, Wg_bf, bg, gatep, nullptr,
                                              8192, 512, 512, 1);
  // attention -> ctx bf16 [8192,64]
  attn_kernel<<<128, 512, 0, stream>>>(qkvT, ctx);
  // attn_out = ctx @ Wo + bo -> fp32 [8192,512]
  gemm_bf16<<<dim3(128, 8), 256, 0, stream>>>(ctx, Wo_bf, bo, ao, nullptr,
                                              8192, 512, 64, 0);
  // out = LN(ao*gate + h)
  ln2_kernel<<<2048, 256, 0, stream>>>(ao, gatep, hF, ln2s, ln2b, out);
}